// Round 1
// baseline (116.735 us; speedup 1.0000x reference)
//
#include <hip/hip_runtime.h>

constexpr int B = 32;
constexpr int T = 128;
constexpr int N = 4096;

__global__ __launch_bounds__(256) void lif_scan_kernel(
    const float* __restrict__ x,
    const float* __restrict__ tau_mem,
    const float* __restrict__ v_th,
    float* __restrict__ out)
{
    const int tid = blockIdx.x * blockDim.x + threadIdx.x;   // 0 .. B*N/2-1
    const int nh  = N / 2;
    const int b   = tid / nh;
    const int n2  = (tid - b * nh) * 2;

    // per-neuron params (clip in fp32 exactly like the reference, then promote)
    float2 tm = *reinterpret_cast<const float2*>(tau_mem + n2);
    float2 tv = *reinterpret_cast<const float2*>(v_th + n2);

    const float tmf0 = fminf(fmaxf(tm.x, 0.8f), 0.98f);
    const float tmf1 = fminf(fmaxf(tm.y, 0.8f), 0.98f);
    const float thf0 = fminf(fmaxf(tv.x, 0.05f), 0.5f);
    const float thf1 = fminf(fmaxf(tv.y, 0.05f), 0.5f);

    const double t0 = (double)tmf0, t1 = (double)tmf1;
    const double c0 = 1.0 - t0,     c1 = 1.0 - t1;
    const double h0 = (double)thf0, h1 = (double)thf1;

    const size_t base = (size_t)b * T * N + (size_t)n2;
    const float* xp = x + base;
    float*       op = out + base;

    double is0 = 0.0, is1 = 0.0, v0 = 0.0, v1 = 0.0;

#pragma unroll 8
    for (int t = 0; t < T; ++t) {
        const float2 xv = *reinterpret_cast<const float2*>(xp + (size_t)t * N);
        // i_syn[t] = 0.5 * i_syn[t-1] + x[t]
        is0 = fma(0.5, is0, (double)xv.x);
        is1 = fma(0.5, is1, (double)xv.y);
        // v[t] = tau * v[t-1] + (1 - tau) * i_syn[t]
        v0 = fma(t0, v0, c0 * is0);
        v1 = fma(t1, v1, c1 * is1);
        float2 s;
        s.x = (v0 >= h0) ? 1.0f : 0.0f;
        s.y = (v1 >= h1) ? 1.0f : 0.0f;
        *reinterpret_cast<float2*>(op + (size_t)t * N) = s;
    }
}

extern "C" void kernel_launch(void* const* d_in, const int* in_sizes, int n_in,
                              void* d_out, int out_size, void* d_ws, size_t ws_size,
                              hipStream_t stream) {
    const float* x       = (const float*)d_in[0];
    const float* tau_mem = (const float*)d_in[1];
    const float* v_th    = (const float*)d_in[2];
    float* out           = (float*)d_out;

    const int threads = B * (N / 2);          // 65536
    dim3 block(256);
    dim3 grid(threads / 256);                 // 256 blocks -> 1 per CU
    lif_scan_kernel<<<grid, block, 0, stream>>>(x, tau_mem, v_th, out);
}